// Round 6
// baseline (692.391 us; speedup 1.0000x reference)
//
#include <hip/hip_runtime.h>

#define NBATCH 2
#define NPTS   8192
#define NPT    (NBATCH*NPTS)
#define KNN    9
#define SEG    16
#define SEGN   (NPTS/SEG)
#define SCAP   12
#define SSTR   13

typedef unsigned short u16;
typedef unsigned int   u32;
typedef short bf16x8 __attribute__((ext_vector_type(8)));
typedef float f32x4  __attribute__((ext_vector_type(4)));

__device__ __forceinline__ float wred(float v){
#pragma unroll
  for(int o=32;o>0;o>>=1) v += __shfl_down(v,o);
  return v;
}

__device__ __forceinline__ u16 f2b(float f){
  u32 u = __float_as_uint(f);
  return (u16)((u + 0x7fffu + ((u>>16)&1u)) >> 16);
}

__device__ __forceinline__ float bumpup(float x){
  u32 u = __float_as_uint(x);
  if(u == 0x80000000u) u = 1u;
  else if((int)u >= 0) u += 1u;
  else u -= 1u;
  return __uint_as_float(u);
}

// ---------------- build point-major feature matrix [pt][196] ----------------
__global__ __launch_bounds__(256) void k_build_xin(
    const float* __restrict__ feats, const float* __restrict__ cost,
    const float* __restrict__ flow, float* __restrict__ xin)
{
  __shared__ float buf[196][67];
  int t = threadIdx.x;
  int pt0 = blockIdx.x*64;
  int b = pt0 >> 13, n0 = pt0 & (NPTS-1);
  int lane = t & 63, grp = t >> 6;
  const float* f  = feats + (size_t)b*128*NPTS + n0 + lane;
  const float* cv = cost  + (size_t)b*64 *NPTS + n0 + lane;
  const float* fl = flow  + (size_t)b*3  *NPTS + n0 + lane;
  for(int c=grp; c<128; c+=4) buf[c][lane]      = f[(size_t)c*NPTS];
  for(int c=grp; c<64;  c+=4) buf[128+c][lane]  = cv[(size_t)c*NPTS];
  if(grp<3) buf[192+grp][lane] = fl[(size_t)grp*NPTS];
  else      buf[195][lane] = 0.f;
  __syncthreads();
  for(int e=t; e<64*49; e+=256){
    int p = e/49, q = e-p*49;
    float4 v = make_float4(buf[4*q][p], buf[4*q+1][p], buf[4*q+2][p], buf[4*q+3][p]);
    *(float4*)(xin + (size_t)(pt0+p)*196 + 4*q) = v;
  }
}

// ---------------- knn pass A: 9th-smallest over stride-16 sample ----------------
__global__ __launch_bounds__(256) void k_thr(
    const float* __restrict__ xyz, float* __restrict__ thr)
{
  __shared__ float md[4][64][9];
  int t = threadIdx.x, lane = t & 63, wave = t >> 6;
  int qb = blockIdx.x;
  int b = qb >> 7;
  int n = (qb & 127)*64 + lane;
  const float* xb = xyz + (size_t)b*NPTS*3;
  float qx=xb[3*n], qy=xb[3*n+1], qz=xb[3*n+2];
  float qs = __fadd_rn(__fadd_rn(__fmul_rn(qx,qx),__fmul_rn(qy,qy)),__fmul_rn(qz,qz));
  float bd[KNN];
#pragma unroll
  for(int i=0;i<KNN;i++) bd[i]=__builtin_inff();
  for(int i=0;i<128;i++){
    int m = (wave*128 + i)*16;
    float cx=xb[3*m], cy=xb[3*m+1], cz=xb[3*m+2];
    float s = __fadd_rn(__fadd_rn(__fmul_rn(cx,cx),__fmul_rn(cy,cy)),__fmul_rn(cz,cz));
    float dot = fmaf(cz,qz, fmaf(cy,qy, __fmul_rn(cx,qx)));
    float d = __fsub_rn(__fadd_rn(qs,s), __fmul_rn(2.0f,dot));
    if(d < bd[KNN-1]){
      bd[KNN-1]=d;
#pragma unroll
      for(int r=KNN-2;r>=0;r--){
        if(bd[r+1] < bd[r]){ float td=bd[r]; bd[r]=bd[r+1]; bd[r+1]=td; }
      }
    }
  }
#pragma unroll
  for(int i=0;i<KNN;i++) md[wave][lane][i]=bd[i];
  __syncthreads();
  if(t < 64){
    float b2[KNN];
#pragma unroll
    for(int i=0;i<KNN;i++) b2[i]=__builtin_inff();
    for(int w=0;w<4;w++){
#pragma unroll
      for(int i=0;i<KNN;i++){
        float d = md[w][t][i];
        if(d < b2[KNN-1]){
          b2[KNN-1]=d;
#pragma unroll
          for(int r=KNN-2;r>=0;r--){
            if(b2[r+1] < b2[r]){ float td=b2[r]; b2[r]=b2[r+1]; b2[r+1]=td; }
          }
        }
      }
    }
    thr[(b<<13) + (qb & 127)*64 + t] = b2[KNN-1];
  }
}

// ---------------- knn pass B: push-buffer top-9 ----------------
__global__ __launch_bounds__(256) void k_knn_part(
    const float* __restrict__ xyz, const float* __restrict__ thr,
    float* __restrict__ pd, int* __restrict__ pi)
{
  __shared__ float4 cbuf[256];
  __shared__ float sdq[256*SSTR];
  __shared__ int   sqi[256*SSTR];
  int t = threadIdx.x;
  int seg = blockIdx.x & (SEG-1);
  int qc  = blockIdx.x >> 4;
  int b = qc >> 5;
  int n = (qc & 31)*256 + t;
  int pt = (b<<13) + n;
  const float* xb = xyz + (size_t)b*NPTS*3;
  float qx=xb[3*n], qy=xb[3*n+1], qz=xb[3*n+2];
  float qs = __fadd_rn(__fadd_rn(__fmul_rn(qx,qx),__fmul_rn(qy,qy)),__fmul_rn(qz,qz));
  float init = bumpup(thr[pt]);
  float bd[KNN]; int bi[KNN];
#pragma unroll
  for(int i=0;i<KNN;i++){ bd[i]=init; bi[i]=0x7fffffff; }
  float cut = init;
  int cnt = 0;
  float* msd = sdq + t*SSTR;
  int*   msi = sqi + t*SSTR;
  auto flush = [&](){
    for(int i=0;i<cnt;i++){
      float d = msd[i]; int id = msi[i];
      if(d < bd[KNN-1]){
        bd[KNN-1]=d; bi[KNN-1]=id;
#pragma unroll
        for(int r=KNN-2;r>=0;r--){
          if(bd[r+1] < bd[r]){
            float td=bd[r]; bd[r]=bd[r+1]; bd[r+1]=td;
            int ti=bi[r]; bi[r]=bi[r+1]; bi[r+1]=ti;
          }
        }
      }
    }
    cnt = 0;
    cut = bd[KNN-1];
  };
  const int m0 = seg*SEGN;
  for(int tt=0; tt<SEGN; tt+=256){
    int m = m0 + tt + t;
    float cx=xb[3*m], cy=xb[3*m+1], cz=xb[3*m+2];
    float s = __fadd_rn(__fadd_rn(__fmul_rn(cx,cx),__fmul_rn(cy,cy)),__fmul_rn(cz,cz));
    cbuf[t] = make_float4(cx,cy,cz,s);
    __syncthreads();
#pragma unroll 4
    for(int j=0;j<256;j++){
      float4 c = cbuf[j];
      float dot = fmaf(c.z,qz, fmaf(c.y,qy, __fmul_rn(c.x,qx)));
      float d = __fsub_rn(__fadd_rn(qs,c.w), __fmul_rn(2.0f,dot));
      if(d < cut){
        msd[cnt]=d; msi[cnt]=m0+tt+j; cnt++;
        if(cnt==SCAP) flush();
      }
    }
    __syncthreads();
  }
  flush();
  size_t base = ((size_t)pt*SEG + seg)*KNN;
#pragma unroll
  for(int i=0;i<KNN;i++){ pd[base+i]=bd[i]; pi[base+i]=bi[i]; }
}

// ---------------- merge ----------------
__global__ __launch_bounds__(256) void k_knn_merge(
    const float* __restrict__ pd, const int* __restrict__ pi, int* __restrict__ idxo)
{
  int pt = blockIdx.x*256 + threadIdx.x;
  const float4* dp = (const float4*)(pd + (size_t)pt*SEG*KNN);
  const int4*   ip = (const int4*)(pi + (size_t)pt*SEG*KNN);
  float bd[KNN]; int bi[KNN];
#pragma unroll
  for(int i=0;i<KNN;i++){ bd[i]=__builtin_inff(); bi[i]=0x7fffffff; }
  for(int v=0; v<SEG*KNN/4; v++){
    float4 dv = dp[v];
    int4   iv = ip[v];
    float dd[4] = {dv.x,dv.y,dv.z,dv.w};
    int   ii[4] = {iv.x,iv.y,iv.z,iv.w};
#pragma unroll
    for(int u=0;u<4;u++){
      float d = dd[u]; int id = ii[u];
      if(d < bd[KNN-1]){
        bd[KNN-1]=d; bi[KNN-1]=id;
#pragma unroll
        for(int i=KNN-2;i>=0;i--){
          if(bd[i+1] < bd[i]){
            float td=bd[i]; bd[i]=bd[i+1]; bd[i+1]=td;
            int ti=bi[i]; bi[i]=bi[i+1]; bi[i+1]=ti;
          }
        }
      }
    }
  }
#pragma unroll
  for(int r=0;r<KNN;r++) idxo[pt*KNN + r] = bi[r];
}

// ---------------- weightnet stage 1 ----------------
__global__ __launch_bounds__(256) void k_wn1(
    const float* __restrict__ xyz, const int* __restrict__ idx,
    const float* __restrict__ W, const float* __restrict__ Bv,
    float* __restrict__ hout, float* __restrict__ partial)
{
  int t = threadIdx.x;
  int e = blockIdx.x*256 + t;
  int pt = e/KNN;
  int b = pt>>13, n = pt & (NPTS-1);
  int m = idx[e];
  const float* xb = xyz + (size_t)b*NPTS*3;
  float gx = xb[3*m]-xb[3*n], gy = xb[3*m+1]-xb[3*n+1], gz = xb[3*m+2]-xb[3*n+2];
  float v[8];
#pragma unroll
  for(int j=0;j<8;j++){
    float d = fmaf(gz, W[3*j+2], fmaf(gy, W[3*j+1], gx*W[3*j]));
    v[j] = d + Bv[j];
    hout[(size_t)e*8 + j] = v[j];
  }
  __shared__ float red[4][2][8];
  int wave = t>>6, lane = t&63;
#pragma unroll
  for(int j=0;j<8;j++){
    float s = wred(v[j]);
    float q = wred(v[j]*v[j]);
    if(lane==0){ red[wave][0][j]=s; red[wave][1][j]=q; }
  }
  __syncthreads();
  if(t < 16){
    int isq = t>>3, c = t&7;
    partial[blockIdx.x*16 + t] =
      red[0][isq][c]+red[1][isq][c]+red[2][isq][c]+red[3][isq][c];
  }
}

// ---------------- weightnet stage 2/3 ----------------
template<int CI, int CO>
__global__ __launch_bounds__(256) void k_wn23(
    const float* __restrict__ hin, const float* __restrict__ st,
    const float* __restrict__ W, const float* __restrict__ Bv,
    float* __restrict__ hout, float* __restrict__ partial)
{
  int t = threadIdx.x;
  int e = blockIdx.x*256 + t;
  float x[CI];
#pragma unroll
  for(int i=0;i<CI;i++){
    float v = (hin[(size_t)e*CI + i] - st[i])*st[CI+i];
    x[i] = v>0.f? v : 0.f;
  }
  float v[CO];
#pragma unroll
  for(int j=0;j<CO;j++){
    float d = 0.f;
#pragma unroll
    for(int i=0;i<CI;i++) d = fmaf(x[i], W[j*CI+i], d);
    v[j] = d + Bv[j];
    hout[(size_t)e*CO + j] = v[j];
  }
  __shared__ float red[4][2][CO];
  int wave = t>>6, lane = t&63;
#pragma unroll
  for(int j=0;j<CO;j++){
    float s = wred(v[j]);
    float q = wred(v[j]*v[j]);
    if(lane==0){ red[wave][0][j]=s; red[wave][1][j]=q; }
  }
  __syncthreads();
  if(t < 2*CO){
    int isq = t/CO, c = t%CO;
    partial[blockIdx.x*2*CO + t] =
      red[0][isq][c]+red[1][isq][c]+red[2][isq][c]+red[3][isq][c];
  }
}

// ---------------- finalize stats ----------------
__global__ __launch_bounds__(256) void k_fin(
    const float* __restrict__ partial, float* __restrict__ st,
    int C, int nb, float cnt)
{
  __shared__ float sa[256], qa[256];
  int t = threadIdx.x;
  int c = t % C;
  int r0 = t / C;
  int stride = 256 / C;
  float s=0.f, q=0.f;
  for(int r=r0; r<nb; r+=stride){
    s += partial[r*2*C + c];
    q += partial[r*2*C + C + c];
  }
  sa[t]=s; qa[t]=q;
  __syncthreads();
  if(t < C){
    for(int g=1; g<stride; g++){ s += sa[t+g*C]; q += qa[t+g*C]; }
    float mean = s/cnt;
    float var  = q/cnt - mean*mean;
    st[t]   = mean;
    st[C+t] = 1.0f/sqrtf(var + 1e-5f);
  }
}

// ---------------- prep W: f32 -> bf16, K-padded, [128][KP] ----------------
__global__ __launch_bounds__(256) void k_prepW(
    const float* __restrict__ linW, u16* __restrict__ Wh, int AW, int KP)
{
  int e = blockIdx.x*256 + threadIdx.x;
  if(e >= 128*KP) return;
  int o = e / KP, k = e - o*KP;
  float w = (k < AW) ? linW[o*AW + k] : 0.f;
  Wh[e] = f2b(w);
}

// ---------------- fused pointconv: gather + weightnet-einsum + MFMA GEMM + stats ----------------
__device__ __forceinline__ void gload16(const void* g, void* l){
  __builtin_amdgcn_global_load_lds(
      (const __attribute__((address_space(1))) u32*)g,
      (__attribute__((address_space(3))) u32*)l, 16, 0, 0);
}

// LDS map (bytes):
//   [0,32768)      Wh double buffer (2 x 128rows x 64k x 2B)
//   [32768,49152)  A double buffer  (2 x 64rows x 64k x 2B), XOR-swizzled chunks
//   [49152,62464)  G gather tile: [64 p][52 floats]: ci*12 + k (k<9), p-stride 52
//   [62464,69376)  gxs [64][9][3]
//   [69376,71680)  si  [64][9]
template<int CIN, int XSTRIDE, int KP>
__global__ __launch_bounds__(256) void k_pcgemm(
    const float* __restrict__ xin, const float* __restrict__ xyz,
    const int* __restrict__ idx, const float* __restrict__ wpre,
    const float* __restrict__ st3, const u16* __restrict__ Wh,
    const float* __restrict__ linb, float* __restrict__ outp,
    float* __restrict__ partial)
{
  constexpr int CPTS = CIN-3;
  constexpr int NT = KP/64;
  __shared__ __attribute__((aligned(16))) char smem[71680];
  u16*   Wlds = (u16*)smem;
  u16*   Alds = (u16*)(smem + 32768);
  float* G    = (float*)(smem + 49152);
  float* gxs  = (float*)(smem + 62464);
  int*   si   = (int*)(smem + 69376);

  int t = threadIdx.x, wave = t>>6, lane = t&63;
  int pt0 = blockIdx.x*64;
  int b = pt0 >> 13;
  const float* xb = xyz + (size_t)b*NPTS*3;
  const float* xbase = xin + ((size_t)(b<<13))*XSTRIDE;

  int p_ = t>>2, wq = t&3;

  // prologue: si, gxs
  for(int e=t; e<64*KNN; e+=256){
    int p = e/KNN, k = e - p*KNN;
    int n = (pt0+p)&(NPTS-1);
    int m = idx[(pt0+p)*KNN+k];
    si[p*KNN+k] = m;
    gxs[(p*KNN+k)*3+0] = xb[3*m]  -xb[3*n];
    gxs[(p*KNN+k)*3+1] = xb[3*m+1]-xb[3*n+1];
    gxs[(p*KNN+k)*3+2] = xb[3*m+2]-xb[3*n+2];
  }
  // per-thread weightnet weights: wm[k][j] for p_ , wn = wq*4+j
  float wm[KNN][4];
  {
    float sm[4], sr[4];
#pragma unroll
    for(int j=0;j<4;j++){ sm[j]=st3[wq*4+j]; sr[j]=st3[16+wq*4+j]; }
#pragma unroll
    for(int k=0;k<KNN;k++){
      float4 w4 = *(const float4*)(wpre + ((size_t)(pt0+p_)*KNN + k)*16 + wq*4);
      float wv[4] = {w4.x,w4.y,w4.z,w4.w};
#pragma unroll
      for(int j=0;j<4;j++){
        float v = (wv[j]-sm[j])*sr[j];
        wm[k][j] = v>0.f? v:0.f;
      }
    }
  }
  __syncthreads();

  auto stageW = [&](int kt, int buf){
    int k0 = kt*64;
#pragma unroll
    for(int r=0;r<4;r++){
      int y  = (r*4 + wave) << 10;
      int yl = y + lane*16;
      int row = yl >> 7;
      int s = (yl >> 4) & 7;
      int c = s ^ (row & 7);
      const u16* src = Wh + (size_t)row*KP + k0 + c*8;
      gload16(src, (char*)smem + buf*16384 + y);
    }
  };

  auto gatherG = [&](int kt){
    int c0 = kt*4;
    for(int e=t; e<64*KNN; e+=256){
      int p = e/KNN, k = e - p*KNN;
      float v[4];
      if(c0+3 < CPTS){
        float4 f4 = *(const float4*)(xbase + (size_t)si[p*KNN+k]*XSTRIDE + c0);
        v[0]=f4.x; v[1]=f4.y; v[2]=f4.z; v[3]=f4.w;
      } else {
#pragma unroll
        for(int j=0;j<4;j++){
          int c = c0+j;
          if(c < CPTS)      v[j] = xbase[(size_t)si[p*KNN+k]*XSTRIDE + c];
          else if(c < CIN)  v[j] = gxs[(p*KNN+k)*3 + (c-CPTS)];
          else              v[j] = 0.f;
        }
      }
#pragma unroll
      for(int j=0;j<4;j++) G[p*52 + j*12 + k] = v[j];
    }
  };

  auto einsumA = [&](int buf){
    float g[4][KNN];
#pragma unroll
    for(int ci=0;ci<4;ci++){
      const float* gp = G + p_*52 + ci*12;
      float4 a4 = *(const float4*)(gp);
      float4 b4 = *(const float4*)(gp+4);
      g[ci][0]=a4.x; g[ci][1]=a4.y; g[ci][2]=a4.z; g[ci][3]=a4.w;
      g[ci][4]=b4.x; g[ci][5]=b4.y; g[ci][6]=b4.z; g[ci][7]=b4.w;
      g[ci][8]=gp[8];
    }
#pragma unroll
    for(int ci=0;ci<4;ci++){
      float a[4];
#pragma unroll
      for(int j=0;j<4;j++){
        float s = 0.f;
#pragma unroll
        for(int k=0;k<KNN;k++) s = fmaf(g[ci][k], wm[k][j], s);
        a[j] = s;
      }
      u32 lo = (u32)f2b(a[0]) | ((u32)f2b(a[1])<<16);
      u32 hi = (u32)f2b(a[2]) | ((u32)f2b(a[3])<<16);
      int chunk = ci*2 + (wq>>1);
      int off = buf*8192 + p_*128 + ((chunk ^ (p_&7))<<4) + (wq&1)*8;
      *(uint2*)((char*)Alds + off) = make_uint2(lo,hi);
    }
  };

  // tile 0
  gatherG(0); stageW(0, 0);
  __syncthreads();
  einsumA(0);
  __syncthreads();

  f32x4 acc[2][4];
#pragma unroll
  for(int i=0;i<2;i++)
#pragma unroll
    for(int j=0;j<4;j++) acc[i][j]=(f32x4)(0.f);

  for(int kt=0; kt<NT; kt++){
    int cur = kt & 1, nxt = cur^1;
    if(kt+1 < NT){ gatherG(kt+1); stageW(kt+1, nxt); }
    __syncthreads();                 // G(kt+1) ready; W(kt+1) DMA drained
    if(kt+1 < NT) einsumA(nxt);
    const u16* Lw = Wlds + cur*8192;
    const u16* La = Alds + cur*4096;
#pragma unroll
    for(int kf=0; kf<2; kf++){
      int cb = kf*4 + (lane>>4);
      bf16x8 af[4];
#pragma unroll
      for(int nf=0; nf<4; nf++){
        int p = nf*16 + (lane&15);
        af[nf] = *(const bf16x8*)(La + p*64 + ((cb ^ (p&7))<<3));
      }
#pragma unroll
      for(int mf=0; mf<2; mf++){
        int row = (wave*2+mf)*16 + (lane&15);
        bf16x8 wh = *(const bf16x8*)(Lw + row*64 + ((cb ^ (row&7))<<3));
#pragma unroll
        for(int nf=0; nf<4; nf++)
          acc[mf][nf] = __builtin_amdgcn_mfma_f32_16x16x32_bf16(wh, af[nf], acc[mf][nf], 0,0,0);
      }
    }
    __syncthreads();                 // A[nxt] complete before next MFMA
  }

  // epilogue: bias + store + per-block bn partials
  int q = lane>>4, lc = lane&15;
#pragma unroll
  for(int mf=0; mf<2; mf++){
    int obase = (wave*2+mf)*16 + q*4;
#pragma unroll
    for(int r=0;r<4;r++){
      int o = obase + r;
      float bo = linb[o];
      float sv = 0.f, qv = 0.f;
#pragma unroll
      for(int nf=0; nf<4; nf++){
        float x = acc[mf][nf][r] + bo;
        outp[(size_t)(pt0 + nf*16 + lc)*128 + o] = x;
        sv += x; qv = fmaf(x,x,qv);
      }
#pragma unroll
      for(int off=8; off>0; off>>=1){
        sv += __shfl_down(sv,off);
        qv += __shfl_down(qv,off);
      }
      if(lc==0){
        partial[blockIdx.x*256 + o]       = sv;
        partial[blockIdx.x*256 + 128 + o] = qv;
      }
    }
  }
}

__global__ __launch_bounds__(256) void k_pfin(
    const float* __restrict__ outp, const float* __restrict__ st,
    float* __restrict__ xout)
{
  int e = blockIdx.x*256 + threadIdx.x;
  int c = e & 127;
  float v = (outp[e]-st[c])*st[128+c];
  xout[e] = v>=0.f? v : 0.1f*v;
}

// ---------------- fused mlp0 + mlp1 + fc ----------------
__global__ __launch_bounds__(256) void k_mlp(
    const float* __restrict__ x2,
    const float* __restrict__ W0, const float* __restrict__ B0,
    const float* __restrict__ W1, const float* __restrict__ B1,
    const float* __restrict__ Wf, const float* __restrict__ Bf,
    float* __restrict__ dout)
{
  __shared__ float w0l[128*129];
  __shared__ float w1l[128*65];
  __shared__ float xt [128*65];
  __shared__ float m1l[64*65];
  int t = threadIdx.x;
  int pt0 = blockIdx.x*64;
  int b = pt0 >> 13, n0 = pt0 & (NPTS-1);
  for(int e=t; e<128*128; e+=256){ int o=e>>7, j=e&127; w0l[j*129+o] = W0[e]; }
  for(int e=t; e<64*128;  e+=256){ int o=e>>7, j=e&127; w1l[j*65+o]  = W1[e]; }
  for(int e=t; e<64*128;  e+=256){ int p=e>>7, j=e&127; xt[j*65+p]   = x2[(size_t)(pt0+p)*128 + j]; }
  __syncthreads();
  int p = t&63, wv = t>>6;
  float acc[32];
#pragma unroll
  for(int i=0;i<32;i++) acc[i]=0.f;
  for(int j=0;j<128;j++){
    float xv = xt[j*65+p];
#pragma unroll
    for(int i=0;i<32;i++)
      acc[i] = fmaf(w0l[j*129 + wv*32 + i], xv, acc[i]);
  }
  __syncthreads();
#pragma unroll
  for(int i=0;i<32;i++){
    float v = acc[i] + B0[wv*32+i];
    v = v>=0.f? v : 0.1f*v;
    xt[(wv*32+i)*65 + p] = v;
  }
  __syncthreads();
  float a2[16];
#pragma unroll
  for(int i=0;i<16;i++) a2[i]=0.f;
  for(int j=0;j<128;j++){
    float xv = xt[j*65+p];
#pragma unroll
    for(int i=0;i<16;i++)
      a2[i] = fmaf(w1l[j*65 + wv*16 + i], xv, a2[i]);
  }
#pragma unroll
  for(int i=0;i<16;i++){
    int o = wv*16+i;
    float v = a2[i] + B1[o];
    v = v>=0.f? v : 0.1f*v;
    dout[(size_t)(b*64+o)*NPTS + n0 + p] = v;
    m1l[o*65+p] = v;
  }
  __syncthreads();
  if(t < 192){
    int o = t/64, pp = t%64;
    float a = Bf[o];
    for(int j=0;j<64;j++) a = fmaf(Wf[o*64+j], m1l[j*65+pp], a);
    a = fminf(fmaxf(a, -200.f), 200.f);
    dout[(size_t)NBATCH*64*NPTS + (size_t)(b*3+o)*NPTS + n0 + pp] = a;
  }
}

extern "C" void kernel_launch(void* const* d_in, const int* in_sizes, int n_in,
                              void* d_out, int out_size, void* d_ws, size_t ws_size,
                              hipStream_t stream)
{
  (void)in_sizes; (void)n_in; (void)out_size; (void)ws_size;
  const float* xyz   = (const float*)d_in[0];
  const float* feats = (const float*)d_in[1];
  const float* cost  = (const float*)d_in[2];
  const float* flow  = (const float*)d_in[3];
  const float* pw1[2]  = {(const float*)d_in[4],  (const float*)d_in[12]};
  const float* pb1[2]  = {(const float*)d_in[5],  (const float*)d_in[13]};
  const float* pw2[2]  = {(const float*)d_in[6],  (const float*)d_in[14]};
  const float* pb2[2]  = {(const float*)d_in[7],  (const float*)d_in[15]};
  const float* pw3[2]  = {(const float*)d_in[8],  (const float*)d_in[16]};
  const float* pb3[2]  = {(const float*)d_in[9],  (const float*)d_in[17]};
  const float* plW[2]  = {(const float*)d_in[10], (const float*)d_in[18]};
  const float* plb[2]  = {(const float*)d_in[11], (const float*)d_in[19]};
  const float* m0W = (const float*)d_in[20];
  const float* m0b = (const float*)d_in[21];
  const float* m1W = (const float*)d_in[22];
  const float* m1b = (const float*)d_in[23];
  const float* fcW = (const float*)d_in[24];
  const float* fcb = (const float*)d_in[25];
  float* out = (float*)d_out;

  const int KP0 = 3200, AW0 = 3168;
  const int KP1 = 2112, AW1 = 2096;

  float* ws = (float*)d_ws;
  size_t o = 0;
  float* xin0 = ws + o; o += (size_t)NPT*196;
  int*   idx  = (int*)(ws + o); o += (size_t)NPT*KNN + 3;
  o &= ~(size_t)3;
  float* thr  = ws + o; o += (size_t)NPT;
  float* pd   = ws + o; o += (size_t)NPT*SEG*KNN;
  int*   pi   = (int*)(ws + o); o += (size_t)NPT*SEG*KNN;
  float* h1   = ws + o; o += (size_t)NPT*KNN*8;
  float* h2   = ws + o; o += (size_t)NPT*KNN*8;
  float* wpre = ws + o; o += (size_t)NPT*KNN*16;
  float* part = ws + o; o += 65536;
  float* st1  = ws + o; o += 16;
  float* st2  = ws + o; o += 16;
  float* st3  = ws + o; o += 32;
  float* sto  = ws + o; o += 256;
  float* outp = ws + o; o += (size_t)NPT*128;
  float* x1   = ws + o; o += (size_t)NPT*128;
  float* x2   = ws + o; o += (size_t)NPT*128;
  u16* Wh0 = (u16*)(ws + o); o += (size_t)128*KP0/2;
  u16* Wh1 = (u16*)(ws + o); o += (size_t)128*KP1/2;

  k_build_xin<<<NPT/64, 256, 0, stream>>>(feats, cost, flow, xin0);
  k_thr<<<256, 256, 0, stream>>>(xyz, thr);
  k_knn_part<<<64*SEG, 256, 0, stream>>>(xyz, thr, pd, pi);
  k_knn_merge<<<NPT/256, 256, 0, stream>>>(pd, pi, idx);

  k_prepW<<<(128*KP0+255)/256, 256, 0, stream>>>(plW[0], Wh0, AW0, KP0);
  k_prepW<<<(128*KP1+255)/256, 256, 0, stream>>>(plW[1], Wh1, AW1, KP1);

  const float cnt1 = (float)(NPT*KNN);
  const float cnto = (float)NPT;

  for(int L=0; L<2; ++L){
    k_wn1<<<576,256,0,stream>>>(xyz, idx, pw1[L], pb1[L], h1, part);
    k_fin<<<1,256,0,stream>>>(part, st1, 8, 576, cnt1);
    k_wn23<8,8><<<576,256,0,stream>>>(h1, st1, pw2[L], pb2[L], h2, part);
    k_fin<<<1,256,0,stream>>>(part, st2, 8, 576, cnt1);
    k_wn23<8,16><<<576,256,0,stream>>>(h2, st2, pw3[L], pb3[L], wpre, part);
    k_fin<<<1,256,0,stream>>>(part, st3, 16, 576, cnt1);
    if(L==0)
      k_pcgemm<198,196,KP0><<<NPT/64,256,0,stream>>>(xin0, xyz, idx, wpre, st3, Wh0, plb[0], outp, part);
    else
      k_pcgemm<131,128,KP1><<<NPT/64,256,0,stream>>>(x1,   xyz, idx, wpre, st3, Wh1, plb[1], outp, part);
    k_fin<<<1,256,0,stream>>>(part, sto, 128, 256, cnto);
    k_pfin<<<NPT*128/256,256,0,stream>>>(outp, sto, (L==0)? x1 : x2);
  }

  k_mlp<<<NPT/64,256,0,stream>>>(x2, m0W,m0b, m1W,m1b, fcW,fcb, out);
}

// Round 7
// 567.443 us; speedup vs baseline: 1.2202x; 1.2202x over previous
//
#include <hip/hip_runtime.h>

#define NBATCH 2
#define NPTS   8192
#define NPT    (NBATCH*NPTS)
#define KNN    9
#define SEG    16
#define SEGN   (NPTS/SEG)
#define SCAP   16
#define SSTR   17

typedef unsigned short u16;
typedef unsigned int   u32;
typedef short bf16x8 __attribute__((ext_vector_type(8)));
typedef float f32x4  __attribute__((ext_vector_type(4)));

__device__ __forceinline__ float wred(float v){
#pragma unroll
  for(int o=32;o>0;o>>=1) v += __shfl_down(v,o);
  return v;
}

__device__ __forceinline__ u16 f2b(float f){
  u32 u = __float_as_uint(f);
  return (u16)((u + 0x7fffu + ((u>>16)&1u)) >> 16);
}

__device__ __forceinline__ float bumpup(float x){
  u32 u = __float_as_uint(x);
  if(u == 0x80000000u) u = 1u;
  else if((int)u >= 0) u += 1u;
  else u -= 1u;
  return __uint_as_float(u);
}

// ---------------- build point-major feature matrix [pt][196] ----------------
__global__ __launch_bounds__(256) void k_build_xin(
    const float* __restrict__ feats, const float* __restrict__ cost,
    const float* __restrict__ flow, float* __restrict__ xin)
{
  __shared__ float buf[196][67];
  int t = threadIdx.x;
  int pt0 = blockIdx.x*64;
  int b = pt0 >> 13, n0 = pt0 & (NPTS-1);
  int lane = t & 63, grp = t >> 6;
  const float* f  = feats + (size_t)b*128*NPTS + n0 + lane;
  const float* cv = cost  + (size_t)b*64 *NPTS + n0 + lane;
  const float* fl = flow  + (size_t)b*3  *NPTS + n0 + lane;
  for(int c=grp; c<128; c+=4) buf[c][lane]      = f[(size_t)c*NPTS];
  for(int c=grp; c<64;  c+=4) buf[128+c][lane]  = cv[(size_t)c*NPTS];
  if(grp<3) buf[192+grp][lane] = fl[(size_t)grp*NPTS];
  else      buf[195][lane] = 0.f;
  __syncthreads();
  for(int e=t; e<64*49; e+=256){
    int p = e/49, q = e-p*49;
    float4 v = make_float4(buf[4*q][p], buf[4*q+1][p], buf[4*q+2][p], buf[4*q+3][p]);
    *(float4*)(xin + (size_t)(pt0+p)*196 + 4*q) = v;
  }
}

// ---------------- knn pass A ----------------
__global__ __launch_bounds__(256) void k_thr(
    const float* __restrict__ xyz, float* __restrict__ thr)
{
  __shared__ float md[4][64][9];
  int t = threadIdx.x, lane = t & 63, wave = t >> 6;
  int qb = blockIdx.x;
  int b = qb >> 7;
  int n = (qb & 127)*64 + lane;
  const float* xb = xyz + (size_t)b*NPTS*3;
  float qx=xb[3*n], qy=xb[3*n+1], qz=xb[3*n+2];
  float qs = __fadd_rn(__fadd_rn(__fmul_rn(qx,qx),__fmul_rn(qy,qy)),__fmul_rn(qz,qz));
  float bd[KNN];
#pragma unroll
  for(int i=0;i<KNN;i++) bd[i]=__builtin_inff();
  for(int i=0;i<128;i++){
    int m = (wave*128 + i)*16;
    float cx=xb[3*m], cy=xb[3*m+1], cz=xb[3*m+2];
    float s = __fadd_rn(__fadd_rn(__fmul_rn(cx,cx),__fmul_rn(cy,cy)),__fmul_rn(cz,cz));
    float dot = fmaf(cz,qz, fmaf(cy,qy, __fmul_rn(cx,qx)));
    float d = __fsub_rn(__fadd_rn(qs,s), __fmul_rn(2.0f,dot));
    if(d < bd[KNN-1]){
      bd[KNN-1]=d;
#pragma unroll
      for(int r=KNN-2;r>=0;r--){
        if(bd[r+1] < bd[r]){ float td=bd[r]; bd[r]=bd[r+1]; bd[r+1]=td; }
      }
    }
  }
#pragma unroll
  for(int i=0;i<KNN;i++) md[wave][lane][i]=bd[i];
  __syncthreads();
  if(t < 64){
    float b2[KNN];
#pragma unroll
    for(int i=0;i<KNN;i++) b2[i]=__builtin_inff();
    for(int w=0;w<4;w++){
#pragma unroll
      for(int i=0;i<KNN;i++){
        float d = md[w][t][i];
        if(d < b2[KNN-1]){
          b2[KNN-1]=d;
#pragma unroll
          for(int r=KNN-2;r>=0;r--){
            if(b2[r+1] < b2[r]){ float td=b2[r]; b2[r]=b2[r+1]; b2[r+1]=td; }
          }
        }
      }
    }
    thr[(b<<13) + (qb & 127)*64 + t] = b2[KNN-1];
  }
}

// ---------------- knn pass B: push-buffer top-9, batched candidate reads ----------------
__global__ __launch_bounds__(256) void k_knn_part(
    const float* __restrict__ xyz, const float* __restrict__ thr,
    float* __restrict__ pd, int* __restrict__ pi)
{
  __shared__ float4 cbuf[256];
  __shared__ float sdq[256*SSTR];
  __shared__ int   sqi[256*SSTR];
  int t = threadIdx.x;
  int seg = blockIdx.x & (SEG-1);
  int qc  = blockIdx.x >> 4;
  int b = qc >> 5;
  int n = (qc & 31)*256 + t;
  int pt = (b<<13) + n;
  const float* xb = xyz + (size_t)b*NPTS*3;
  float qx=xb[3*n], qy=xb[3*n+1], qz=xb[3*n+2];
  float qs = __fadd_rn(__fadd_rn(__fmul_rn(qx,qx),__fmul_rn(qy,qy)),__fmul_rn(qz,qz));
  float init = bumpup(thr[pt]);
  float bd[KNN]; int bi[KNN];
#pragma unroll
  for(int i=0;i<KNN;i++){ bd[i]=init; bi[i]=0x7fffffff; }
  float cut = init;
  int cnt = 0;
  float* msd = sdq + t*SSTR;
  int*   msi = sqi + t*SSTR;
  auto flush = [&](){
    for(int i=0;i<cnt;i++){
      float d = msd[i]; int id = msi[i];
      if(d < bd[KNN-1]){
        bd[KNN-1]=d; bi[KNN-1]=id;
#pragma unroll
        for(int r=KNN-2;r>=0;r--){
          if(bd[r+1] < bd[r]){
            float td=bd[r]; bd[r]=bd[r+1]; bd[r+1]=td;
            int ti=bi[r]; bi[r]=bi[r+1]; bi[r+1]=ti;
          }
        }
      }
    }
    cnt = 0;
    cut = bd[KNN-1];
  };
  const int m0 = seg*SEGN;
  for(int tt=0; tt<SEGN; tt+=256){
    int m = m0 + tt + t;
    float cx=xb[3*m], cy=xb[3*m+1], cz=xb[3*m+2];
    float s = __fadd_rn(__fadd_rn(__fmul_rn(cx,cx),__fmul_rn(cy,cy)),__fmul_rn(cz,cz));
    cbuf[t] = make_float4(cx,cy,cz,s);
    __syncthreads();
    for(int j0=0; j0<256; j0+=8){
      float dv[8];
#pragma unroll
      for(int u=0;u<8;u++){
        float4 c = cbuf[j0+u];
        float dot = fmaf(c.z,qz, fmaf(c.y,qy, __fmul_rn(c.x,qx)));
        dv[u] = __fsub_rn(__fadd_rn(qs,c.w), __fmul_rn(2.0f,dot));
      }
#pragma unroll
      for(int u=0;u<8;u++){
        if(dv[u] < cut){
          msd[cnt]=dv[u]; msi[cnt]=m0+tt+j0+u; cnt++;
          if(cnt==SCAP) flush();
        }
      }
    }
    __syncthreads();
  }
  flush();
  size_t base = ((size_t)pt*SEG + seg)*KNN;
#pragma unroll
  for(int i=0;i<KNN;i++){ pd[base+i]=bd[i]; pi[base+i]=bi[i]; }
}

// ---------------- merge ----------------
__global__ __launch_bounds__(256) void k_knn_merge(
    const float* __restrict__ pd, const int* __restrict__ pi, int* __restrict__ idxo)
{
  int pt = blockIdx.x*256 + threadIdx.x;
  const float4* dp = (const float4*)(pd + (size_t)pt*SEG*KNN);
  const int4*   ip = (const int4*)(pi + (size_t)pt*SEG*KNN);
  float bd[KNN]; int bi[KNN];
#pragma unroll
  for(int i=0;i<KNN;i++){ bd[i]=__builtin_inff(); bi[i]=0x7fffffff; }
  for(int v=0; v<SEG*KNN/4; v++){
    float4 dv = dp[v];
    int4   iv = ip[v];
    float dd[4] = {dv.x,dv.y,dv.z,dv.w};
    int   ii[4] = {iv.x,iv.y,iv.z,iv.w};
#pragma unroll
    for(int u=0;u<4;u++){
      float d = dd[u]; int id = ii[u];
      if(d < bd[KNN-1]){
        bd[KNN-1]=d; bi[KNN-1]=id;
#pragma unroll
        for(int i=KNN-2;i>=0;i--){
          if(bd[i+1] < bd[i]){
            float td=bd[i]; bd[i]=bd[i+1]; bd[i+1]=td;
            int ti=bi[i]; bi[i]=bi[i+1]; bi[i+1]=ti;
          }
        }
      }
    }
  }
#pragma unroll
  for(int r=0;r<KNN;r++) idxo[pt*KNN + r] = bi[r];
}

// ---------------- weightnet stage 1 ----------------
__global__ __launch_bounds__(256) void k_wn1(
    const float* __restrict__ xyz, const int* __restrict__ idx,
    const float* __restrict__ W, const float* __restrict__ Bv,
    float* __restrict__ hout, float* __restrict__ partial)
{
  int t = threadIdx.x;
  int e = blockIdx.x*256 + t;
  int pt = e/KNN;
  int b = pt>>13, n = pt & (NPTS-1);
  int m = idx[e];
  const float* xb = xyz + (size_t)b*NPTS*3;
  float gx = xb[3*m]-xb[3*n], gy = xb[3*m+1]-xb[3*n+1], gz = xb[3*m+2]-xb[3*n+2];
  float v[8];
#pragma unroll
  for(int j=0;j<8;j++){
    float d = fmaf(gz, W[3*j+2], fmaf(gy, W[3*j+1], gx*W[3*j]));
    v[j] = d + Bv[j];
    hout[(size_t)e*8 + j] = v[j];
  }
  __shared__ float red[4][2][8];
  int wave = t>>6, lane = t&63;
#pragma unroll
  for(int j=0;j<8;j++){
    float s = wred(v[j]);
    float q = wred(v[j]*v[j]);
    if(lane==0){ red[wave][0][j]=s; red[wave][1][j]=q; }
  }
  __syncthreads();
  if(t < 16){
    int isq = t>>3, c = t&7;
    partial[blockIdx.x*16 + t] =
      red[0][isq][c]+red[1][isq][c]+red[2][isq][c]+red[3][isq][c];
  }
}

// ---------------- weightnet stage 2/3 ----------------
template<int CI, int CO>
__global__ __launch_bounds__(256) void k_wn23(
    const float* __restrict__ hin, const float* __restrict__ st,
    const float* __restrict__ W, const float* __restrict__ Bv,
    float* __restrict__ hout, float* __restrict__ partial)
{
  int t = threadIdx.x;
  int e = blockIdx.x*256 + t;
  float x[CI];
#pragma unroll
  for(int i=0;i<CI;i++){
    float v = (hin[(size_t)e*CI + i] - st[i])*st[CI+i];
    x[i] = v>0.f? v : 0.f;
  }
  float v[CO];
#pragma unroll
  for(int j=0;j<CO;j++){
    float d = 0.f;
#pragma unroll
    for(int i=0;i<CI;i++) d = fmaf(x[i], W[j*CI+i], d);
    v[j] = d + Bv[j];
    hout[(size_t)e*CO + j] = v[j];
  }
  __shared__ float red[4][2][CO];
  int wave = t>>6, lane = t&63;
#pragma unroll
  for(int j=0;j<CO;j++){
    float s = wred(v[j]);
    float q = wred(v[j]*v[j]);
    if(lane==0){ red[wave][0][j]=s; red[wave][1][j]=q; }
  }
  __syncthreads();
  if(t < 2*CO){
    int isq = t/CO, c = t%CO;
    partial[blockIdx.x*2*CO + t] =
      red[0][isq][c]+red[1][isq][c]+red[2][isq][c]+red[3][isq][c];
  }
}

// ---------------- finalize stats ----------------
__global__ __launch_bounds__(256) void k_fin(
    const float* __restrict__ partial, float* __restrict__ st,
    int C, int nb, float cnt)
{
  __shared__ float sa[256], qa[256];
  int t = threadIdx.x;
  int c = t % C;
  int r0 = t / C;
  int stride = 256 / C;
  float s=0.f, q=0.f;
  for(int r=r0; r<nb; r+=stride){
    s += partial[r*2*C + c];
    q += partial[r*2*C + C + c];
  }
  sa[t]=s; qa[t]=q;
  __syncthreads();
  if(t < C){
    for(int g=1; g<stride; g++){ s += sa[t+g*C]; q += qa[t+g*C]; }
    float mean = s/cnt;
    float var  = q/cnt - mean*mean;
    st[t]   = mean;
    st[C+t] = 1.0f/sqrtf(var + 1e-5f);
  }
}

// ---------------- prep W: f32 -> bf16, K-padded, [128][KP] ----------------
__global__ __launch_bounds__(256) void k_prepW(
    const float* __restrict__ linW, u16* __restrict__ Wh, int AW, int KP)
{
  int e = blockIdx.x*256 + threadIdx.x;
  if(e >= 128*KP) return;
  int o = e / KP, k = e - o*KP;
  float w = (k < AW) ? linW[o*AW + k] : 0.f;
  Wh[e] = f2b(w);
}

// ---------------- build A (gather + weightnet einsum) -> bf16 [row][KP] ----------------
template<int CIN, int XSTRIDE, int KP>
__global__ __launch_bounds__(256) void k_buildA(
    const float* __restrict__ xin, const float* __restrict__ xyz,
    const int* __restrict__ idx, const float* __restrict__ wpre,
    const float* __restrict__ st3, u16* __restrict__ Abuf, int c0)
{
  constexpr int P = 8;
  constexpr int CPTS = CIN-3;
  constexpr int CPAD = KP/16;
  __shared__ float wm[P][KNN][16];
  __shared__ float gxs[P][KNN][3];
  __shared__ int   si[P][KNN];
  __shared__ float sm3[16], sr3[16];
  int t = threadIdx.x;
  int pt0 = c0 + blockIdx.x*P;
  int b = pt0 >> 13;
  const float* xb = xyz + (size_t)b*NPTS*3;
  if(t<16){ sm3[t]=st3[t]; sr3[t]=st3[16+t]; }
  if(t>=32 && t<32+P*KNN){
    int u = t-32; int p=u/KNN, k=u-p*KNN;
    int n = (pt0+p)&(NPTS-1);
    int m = idx[(pt0+p)*KNN+k];
    si[p][k]=m;
    gxs[p][k][0]=xb[3*m]  -xb[3*n];
    gxs[p][k][1]=xb[3*m+1]-xb[3*n+1];
    gxs[p][k][2]=xb[3*m+2]-xb[3*n+2];
  }
  __syncthreads();
  for(int e=t; e<P*KNN*16; e+=256){
    int p = e/(KNN*16); int r = e - p*(KNN*16); int k = r>>4, wn = r&15;
    float v = (wpre[((size_t)(pt0+p)*KNN + k)*16 + wn] - sm3[wn]) * sr3[wn];
    wm[p][k][wn] = v>0.f? v:0.f;
  }
  __syncthreads();
  for(int it=t; it<P*CPAD; it+=256){
    int p = it/CPAD, c = it - p*CPAD;
    u32 u[8];
    if(c < CIN){
      float g[KNN];
      if(c < CPTS){
#pragma unroll
        for(int k=0;k<KNN;k++)
          g[k] = xin[(size_t)((b<<13) + si[p][k])*XSTRIDE + c];
      } else {
        int cc = c - CPTS;
#pragma unroll
        for(int k=0;k<KNN;k++) g[k] = gxs[p][k][cc];
      }
      float a[16];
#pragma unroll
      for(int wn=0; wn<16; wn++){
        float s = 0.f;
#pragma unroll
        for(int k=0;k<KNN;k++) s = fmaf(g[k], wm[p][k][wn], s);
        a[wn] = s;
      }
#pragma unroll
      for(int j=0;j<8;j++)
        u[j] = (u32)f2b(a[2*j]) | ((u32)f2b(a[2*j+1])<<16);
    } else {
#pragma unroll
      for(int j=0;j<8;j++) u[j]=0;
    }
    u32* dst = (u32*)(Abuf + ((size_t)(blockIdx.x*P + p)*KP + c*16));
    uint4 v0 = make_uint4(u[0],u[1],u[2],u[3]);
    uint4 v1 = make_uint4(u[4],u[5],u[6],u[7]);
    *(uint4*)dst = v0;
    *((uint4*)dst + 1) = v1;
  }
}

// ---------------- MFMA GEMM (single-W) + fused bn stats ----------------
__device__ __forceinline__ void gload16(const void* g, void* l){
  __builtin_amdgcn_global_load_lds(
      (const __attribute__((address_space(1))) u32*)g,
      (__attribute__((address_space(3))) u32*)l, 16, 0, 0);
}

template<int KP>
__global__ __launch_bounds__(256) void k_gemm(
    const u16* __restrict__ Wh, const u16* __restrict__ A,
    const float* __restrict__ linb, float* __restrict__ outp,
    float* __restrict__ partial, int ptBase)
{
  // LDS: Wh dbuf 2x16KB @0, A dbuf 2x8KB @32768  (48 KiB)
  __shared__ __attribute__((aligned(16))) u16 lds[24576];
  constexpr int NT = KP/64;
  int t = threadIdx.x, wave = t>>6, lane = t&63;
  int p0 = blockIdx.x*64;
  const u16* Ab = A + (size_t)p0*KP;

  auto stage = [&](const u16* __restrict__ g, int k0, int ldsByteOff, int rows){
    int nr = (rows*128) >> 12;
    for(int r=0;r<nr;r++){
      int y  = (r*4 + wave) << 10;
      int yl = y + lane*16;
      int row = yl >> 7;
      int s = (yl >> 4) & 7;
      int c = s ^ (row & 7);
      const u16* src = g + (size_t)row*KP + k0 + c*8;
      gload16(src, (char*)lds + ldsByteOff + y);
    }
  };

  stage(Wh, 0, 0,     128);
  stage(Ab, 0, 32768, 64);

  f32x4 acc[2][4];
#pragma unroll
  for(int i=0;i<2;i++)
#pragma unroll
    for(int j=0;j<4;j++) acc[i][j]=(f32x4)(0.f);

  for(int kt=0; kt<NT; kt++){
    int cur = kt & 1;
    __syncthreads();
    if(kt+1 < NT){
      int nxt = cur^1;
      stage(Wh, (kt+1)*64, nxt*16384,         128);
      stage(Ab, (kt+1)*64, 32768 + nxt*8192,  64);
    }
    const u16* Lw = lds + cur*8192;
    const u16* La = lds + 16384 + cur*4096;
#pragma unroll
    for(int kf=0; kf<2; kf++){
      int cb = kf*4 + (lane>>4);
      bf16x8 af[4];
#pragma unroll
      for(int nf=0; nf<4; nf++){
        int p = nf*16 + (lane&15);
        af[nf] = *(const bf16x8*)(La + p*64 + ((cb ^ (p&7))<<3));
      }
#pragma unroll
      for(int mf=0; mf<2; mf++){
        int row = (wave*2+mf)*16 + (lane&15);
        bf16x8 wh = *(const bf16x8*)(Lw + row*64 + ((cb ^ (row&7))<<3));
#pragma unroll
        for(int nf=0; nf<4; nf++)
          acc[mf][nf] = __builtin_amdgcn_mfma_f32_16x16x32_bf16(wh, af[nf], acc[mf][nf], 0,0,0);
      }
    }
  }

  // epilogue: bias + store + per-block bn partials
  int gb = (ptBase>>6) + blockIdx.x;
  int q = lane>>4, lc = lane&15;
#pragma unroll
  for(int mf=0; mf<2; mf++){
    int obase = (wave*2+mf)*16 + q*4;
#pragma unroll
    for(int r=0;r<4;r++){
      int o = obase + r;
      float bo = linb[o];
      float sv = 0.f, qv = 0.f;
#pragma unroll
      for(int nf=0; nf<4; nf++){
        float x = acc[mf][nf][r] + bo;
        outp[(size_t)(ptBase + p0 + nf*16 + lc)*128 + o] = x;
        sv += x; qv = fmaf(x,x,qv);
      }
#pragma unroll
      for(int off=8; off>0; off>>=1){
        sv += __shfl_down(sv,off);
        qv += __shfl_down(qv,off);
      }
      if(lc==0){
        partial[gb*256 + o]       = sv;
        partial[gb*256 + 128 + o] = qv;
      }
    }
  }
}

__global__ __launch_bounds__(256) void k_pfin(
    const float* __restrict__ outp, const float* __restrict__ st,
    float* __restrict__ xout)
{
  int e = blockIdx.x*256 + threadIdx.x;
  int c = e & 127;
  float v = (outp[e]-st[c])*st[128+c];
  xout[e] = v>=0.f? v : 0.1f*v;
}

// ---------------- fused mlp0 + mlp1 + fc ----------------
__global__ __launch_bounds__(256) void k_mlp(
    const float* __restrict__ x2,
    const float* __restrict__ W0, const float* __restrict__ B0,
    const float* __restrict__ W1, const float* __restrict__ B1,
    const float* __restrict__ Wf, const float* __restrict__ Bf,
    float* __restrict__ dout)
{
  __shared__ float w0l[128*129];
  __shared__ float w1l[128*65];
  __shared__ float xt [128*65];
  __shared__ float m1l[64*65];
  int t = threadIdx.x;
  int pt0 = blockIdx.x*64;
  int b = pt0 >> 13, n0 = pt0 & (NPTS-1);
  for(int e=t; e<128*128; e+=256){ int o=e>>7, j=e&127; w0l[j*129+o] = W0[e]; }
  for(int e=t; e<64*128;  e+=256){ int o=e>>7, j=e&127; w1l[j*65+o]  = W1[e]; }
  for(int e=t; e<64*128;  e+=256){ int p=e>>7, j=e&127; xt[j*65+p]   = x2[(size_t)(pt0+p)*128 + j]; }
  __syncthreads();
  int p = t&63, wv = t>>6;
  float acc[32];
#pragma unroll
  for(int i=0;i<32;i++) acc[i]=0.f;
  for(int j=0;j<128;j++){
    float xv = xt[j*65+p];
#pragma unroll
    for(int i=0;i<32;i++)
      acc[i] = fmaf(w0l[j*129 + wv*32 + i], xv, acc[i]);
  }
  __syncthreads();
#pragma unroll
  for(int i=0;i<32;i++){
    float v = acc[i] + B0[wv*32+i];
    v = v>=0.f? v : 0.1f*v;
    xt[(wv*32+i)*65 + p] = v;
  }
  __syncthreads();
  float a2[16];
#pragma unroll
  for(int i=0;i<16;i++) a2[i]=0.f;
  for(int j=0;j<128;j++){
    float xv = xt[j*65+p];
#pragma unroll
    for(int i=0;i<16;i++)
      a2[i] = fmaf(w1l[j*65 + wv*16 + i], xv, a2[i]);
  }
#pragma unroll
  for(int i=0;i<16;i++){
    int o = wv*16+i;
    float v = a2[i] + B1[o];
    v = v>=0.f? v : 0.1f*v;
    dout[(size_t)(b*64+o)*NPTS + n0 + p] = v;
    m1l[o*65+p] = v;
  }
  __syncthreads();
  if(t < 192){
    int o = t/64, pp = t%64;
    float a = Bf[o];
    for(int j=0;j<64;j++) a = fmaf(Wf[o*64+j], m1l[j*65+pp], a);
    a = fminf(fmaxf(a, -200.f), 200.f);
    dout[(size_t)NBATCH*64*NPTS + (size_t)(b*3+o)*NPTS + n0 + pp] = a;
  }
}

extern "C" void kernel_launch(void* const* d_in, const int* in_sizes, int n_in,
                              void* d_out, int out_size, void* d_ws, size_t ws_size,
                              hipStream_t stream)
{
  (void)in_sizes; (void)n_in; (void)out_size;
  const float* xyz   = (const float*)d_in[0];
  const float* feats = (const float*)d_in[1];
  const float* cost  = (const float*)d_in[2];
  const float* flow  = (const float*)d_in[3];
  const float* pw1[2]  = {(const float*)d_in[4],  (const float*)d_in[12]};
  const float* pb1[2]  = {(const float*)d_in[5],  (const float*)d_in[13]};
  const float* pw2[2]  = {(const float*)d_in[6],  (const float*)d_in[14]};
  const float* pb2[2]  = {(const float*)d_in[7],  (const float*)d_in[15]};
  const float* pw3[2]  = {(const float*)d_in[8],  (const float*)d_in[16]};
  const float* pb3[2]  = {(const float*)d_in[9],  (const float*)d_in[17]};
  const float* plW[2]  = {(const float*)d_in[10], (const float*)d_in[18]};
  const float* plb[2]  = {(const float*)d_in[11], (const float*)d_in[19]};
  const float* m0W = (const float*)d_in[20];
  const float* m0b = (const float*)d_in[21];
  const float* m1W = (const float*)d_in[22];
  const float* m1b = (const float*)d_in[23];
  const float* fcW = (const float*)d_in[24];
  const float* fcb = (const float*)d_in[25];
  float* out = (float*)d_out;

  const int KP0 = 3200, AW0 = 3168;
  const int KP1 = 2112, AW1 = 2096;

  float* ws = (float*)d_ws;
  size_t o = 0;
  float* xin0 = ws + o; o += (size_t)NPT*196;
  int*   idx  = (int*)(ws + o); o += (size_t)NPT*KNN + 3;
  o &= ~(size_t)3;
  float* thr  = ws + o; o += (size_t)NPT;
  float* pd   = ws + o; o += (size_t)NPT*SEG*KNN;
  int*   pi   = (int*)(ws + o); o += (size_t)NPT*SEG*KNN;
  float* h1   = ws + o; o += (size_t)NPT*KNN*8;
  float* h2   = ws + o; o += (size_t)NPT*KNN*8;
  float* wpre = ws + o; o += (size_t)NPT*KNN*16;
  float* part = ws + o; o += 65536;
  float* st1  = ws + o; o += 16;
  float* st2  = ws + o; o += 16;
  float* st3  = ws + o; o += 32;
  float* sto  = ws + o; o += 256;
  float* outp = ws + o; o += (size_t)NPT*128;
  float* x1   = ws + o; o += (size_t)NPT*128;
  float* x2   = ws + o; o += (size_t)NPT*128;
  u16* Wh0 = (u16*)(ws + o); o += (size_t)128*KP0/2;
  u16* Wh1 = (u16*)(ws + o); o += (size_t)128*KP1/2;
  u16* Abuf = (u16*)(ws + o);
  size_t used_bytes = o*4;
  size_t avail = ws_size > used_bytes ? ws_size - used_bytes : 0;
  int npc = NPT;
  while(npc > 1024 && (size_t)npc*KP0*2 > avail) npc >>= 1;

  k_build_xin<<<NPT/64, 256, 0, stream>>>(feats, cost, flow, xin0);
  k_thr<<<256, 256, 0, stream>>>(xyz, thr);
  k_knn_part<<<64*SEG, 256, 0, stream>>>(xyz, thr, pd, pi);
  k_knn_merge<<<NPT/256, 256, 0, stream>>>(pd, pi, idx);

  k_prepW<<<(128*KP0+255)/256, 256, 0, stream>>>(plW[0], Wh0, AW0, KP0);
  k_prepW<<<(128*KP1+255)/256, 256, 0, stream>>>(plW[1], Wh1, AW1, KP1);

  const float cnt1 = (float)(NPT*KNN);
  const float cnto = (float)NPT;

  for(int L=0; L<2; ++L){
    k_wn1<<<576,256,0,stream>>>(xyz, idx, pw1[L], pb1[L], h1, part);
    k_fin<<<1,256,0,stream>>>(part, st1, 8, 576, cnt1);
    k_wn23<8,8><<<576,256,0,stream>>>(h1, st1, pw2[L], pb2[L], h2, part);
    k_fin<<<1,256,0,stream>>>(part, st2, 8, 576, cnt1);
    k_wn23<8,16><<<576,256,0,stream>>>(h2, st2, pw3[L], pb3[L], wpre, part);
    k_fin<<<1,256,0,stream>>>(part, st3, 16, 576, cnt1);
    for(int c0 = 0; c0 < NPT; c0 += npc){
      if(L==0){
        k_buildA<198,196,KP0><<<npc/8,256,0,stream>>>(xin0, xyz, idx, wpre, st3, Abuf, c0);
        k_gemm<KP0><<<npc/64,256,0,stream>>>(Wh0, Abuf, plb[0], outp, part, c0);
      } else {
        k_buildA<131,128,KP1><<<npc/8,256,0,stream>>>(x1, xyz, idx, wpre, st3, Abuf, c0);
        k_gemm<KP1><<<npc/64,256,0,stream>>>(Wh1, Abuf, plb[1], outp, part, c0);
      }
    }
    k_fin<<<1,256,0,stream>>>(part, sto, 128, NPT/64, cnto);
    k_pfin<<<NPT*128/256,256,0,stream>>>(outp, sto, (L==0)? x1 : x2);
  }

  k_mlp<<<NPT/64,256,0,stream>>>(x2, m0W,m0b, m1W,m1b, fcW,fcb, out);
}

// Round 8
// 561.211 us; speedup vs baseline: 1.2337x; 1.0111x over previous
//
#include <hip/hip_runtime.h>

#define NBATCH 2
#define NPTS   8192
#define NPT    (NBATCH*NPTS)
#define KNN    9
#define SEG    16
#define SEGN   (NPTS/SEG)
#define SCAP   16
#define SSTR   17

typedef unsigned short u16;
typedef unsigned int   u32;
typedef short bf16x8 __attribute__((ext_vector_type(8)));
typedef float f32x4  __attribute__((ext_vector_type(4)));

__device__ __forceinline__ float wred(float v){
#pragma unroll
  for(int o=32;o>0;o>>=1) v += __shfl_down(v,o);
  return v;
}

__device__ __forceinline__ u16 f2b(float f){
  u32 u = __float_as_uint(f);
  return (u16)((u + 0x7fffu + ((u>>16)&1u)) >> 16);
}

__device__ __forceinline__ float bumpup(float x){
  u32 u = __float_as_uint(x);
  if(u == 0x80000000u) u = 1u;
  else if((int)u >= 0) u += 1u;
  else u -= 1u;
  return __uint_as_float(u);
}

// ---------------- build point-major feature matrix [pt][196] ----------------
__global__ __launch_bounds__(256) void k_build_xin(
    const float* __restrict__ feats, const float* __restrict__ cost,
    const float* __restrict__ flow, float* __restrict__ xin)
{
  __shared__ float buf[196][67];
  int t = threadIdx.x;
  int pt0 = blockIdx.x*64;
  int b = pt0 >> 13, n0 = pt0 & (NPTS-1);
  int lane = t & 63, grp = t >> 6;
  const float* f  = feats + (size_t)b*128*NPTS + n0 + lane;
  const float* cv = cost  + (size_t)b*64 *NPTS + n0 + lane;
  const float* fl = flow  + (size_t)b*3  *NPTS + n0 + lane;
  for(int c=grp; c<128; c+=4) buf[c][lane]      = f[(size_t)c*NPTS];
  for(int c=grp; c<64;  c+=4) buf[128+c][lane]  = cv[(size_t)c*NPTS];
  if(grp<3) buf[192+grp][lane] = fl[(size_t)grp*NPTS];
  else      buf[195][lane] = 0.f;
  __syncthreads();
  for(int e=t; e<64*49; e+=256){
    int p = e/49, q = e-p*49;
    float4 v = make_float4(buf[4*q][p], buf[4*q+1][p], buf[4*q+2][p], buf[4*q+3][p]);
    *(float4*)(xin + (size_t)(pt0+p)*196 + 4*q) = v;
  }
}

// ---------------- knn pass A ----------------
__global__ __launch_bounds__(256) void k_thr(
    const float* __restrict__ xyz, float* __restrict__ thr)
{
  __shared__ float md[4][64][9];
  int t = threadIdx.x, lane = t & 63, wave = t >> 6;
  int qb = blockIdx.x;
  int b = qb >> 7;
  int n = (qb & 127)*64 + lane;
  const float* xb = xyz + (size_t)b*NPTS*3;
  float qx=xb[3*n], qy=xb[3*n+1], qz=xb[3*n+2];
  float qs = __fadd_rn(__fadd_rn(__fmul_rn(qx,qx),__fmul_rn(qy,qy)),__fmul_rn(qz,qz));
  float bd[KNN];
#pragma unroll
  for(int i=0;i<KNN;i++) bd[i]=__builtin_inff();
  for(int i=0;i<128;i++){
    int m = (wave*128 + i)*16;
    float cx=xb[3*m], cy=xb[3*m+1], cz=xb[3*m+2];
    float s = __fadd_rn(__fadd_rn(__fmul_rn(cx,cx),__fmul_rn(cy,cy)),__fmul_rn(cz,cz));
    float dot = fmaf(cz,qz, fmaf(cy,qy, __fmul_rn(cx,qx)));
    float d = __fsub_rn(__fadd_rn(qs,s), __fmul_rn(2.0f,dot));
    if(d < bd[KNN-1]){
      bd[KNN-1]=d;
#pragma unroll
      for(int r=KNN-2;r>=0;r--){
        if(bd[r+1] < bd[r]){ float td=bd[r]; bd[r]=bd[r+1]; bd[r+1]=td; }
      }
    }
  }
#pragma unroll
  for(int i=0;i<KNN;i++) md[wave][lane][i]=bd[i];
  __syncthreads();
  if(t < 64){
    float b2[KNN];
#pragma unroll
    for(int i=0;i<KNN;i++) b2[i]=__builtin_inff();
    for(int w=0;w<4;w++){
#pragma unroll
      for(int i=0;i<KNN;i++){
        float d = md[w][t][i];
        if(d < b2[KNN-1]){
          b2[KNN-1]=d;
#pragma unroll
          for(int r=KNN-2;r>=0;r--){
            if(b2[r+1] < b2[r]){ float td=b2[r]; b2[r]=b2[r+1]; b2[r+1]=td; }
          }
        }
      }
    }
    thr[(b<<13) + (qb & 127)*64 + t] = b2[KNN-1];
  }
}

// ---------------- knn pass B: push-buffer top-9, batched candidate reads ----------------
__global__ __launch_bounds__(256) void k_knn_part(
    const float* __restrict__ xyz, const float* __restrict__ thr,
    float* __restrict__ pd, int* __restrict__ pi)
{
  __shared__ float4 cbuf[256];
  __shared__ float sdq[256*SSTR];
  __shared__ int   sqi[256*SSTR];
  int t = threadIdx.x;
  int seg = blockIdx.x & (SEG-1);
  int qc  = blockIdx.x >> 4;
  int b = qc >> 5;
  int n = (qc & 31)*256 + t;
  int pt = (b<<13) + n;
  const float* xb = xyz + (size_t)b*NPTS*3;
  float qx=xb[3*n], qy=xb[3*n+1], qz=xb[3*n+2];
  float qs = __fadd_rn(__fadd_rn(__fmul_rn(qx,qx),__fmul_rn(qy,qy)),__fmul_rn(qz,qz));
  float init = bumpup(thr[pt]);
  float bd[KNN]; int bi[KNN];
#pragma unroll
  for(int i=0;i<KNN;i++){ bd[i]=init; bi[i]=0x7fffffff; }
  float cut = init;
  int cnt = 0;
  float* msd = sdq + t*SSTR;
  int*   msi = sqi + t*SSTR;
  auto flush = [&](){
    for(int i=0;i<cnt;i++){
      float d = msd[i]; int id = msi[i];
      if(d < bd[KNN-1]){
        bd[KNN-1]=d; bi[KNN-1]=id;
#pragma unroll
        for(int r=KNN-2;r>=0;r--){
          if(bd[r+1] < bd[r]){
            float td=bd[r]; bd[r]=bd[r+1]; bd[r+1]=td;
            int ti=bi[r]; bi[r]=bi[r+1]; bi[r+1]=ti;
          }
        }
      }
    }
    cnt = 0;
    cut = bd[KNN-1];
  };
  const int m0 = seg*SEGN;
  for(int tt=0; tt<SEGN; tt+=256){
    int m = m0 + tt + t;
    float cx=xb[3*m], cy=xb[3*m+1], cz=xb[3*m+2];
    float s = __fadd_rn(__fadd_rn(__fmul_rn(cx,cx),__fmul_rn(cy,cy)),__fmul_rn(cz,cz));
    cbuf[t] = make_float4(cx,cy,cz,s);
    __syncthreads();
    for(int j0=0; j0<256; j0+=8){
      float dv[8];
#pragma unroll
      for(int u=0;u<8;u++){
        float4 c = cbuf[j0+u];
        float dot = fmaf(c.z,qz, fmaf(c.y,qy, __fmul_rn(c.x,qx)));
        dv[u] = __fsub_rn(__fadd_rn(qs,c.w), __fmul_rn(2.0f,dot));
      }
#pragma unroll
      for(int u=0;u<8;u++){
        if(dv[u] < cut){
          msd[cnt]=dv[u]; msi[cnt]=m0+tt+j0+u; cnt++;
          if(cnt==SCAP) flush();
        }
      }
    }
    __syncthreads();
  }
  flush();
  size_t base = ((size_t)pt*SEG + seg)*KNN;
#pragma unroll
  for(int i=0;i<KNN;i++){ pd[base+i]=bd[i]; pi[base+i]=bi[i]; }
}

// ---------------- merge ----------------
__global__ __launch_bounds__(256) void k_knn_merge(
    const float* __restrict__ pd, const int* __restrict__ pi, int* __restrict__ idxo)
{
  int pt = blockIdx.x*256 + threadIdx.x;
  const float4* dp = (const float4*)(pd + (size_t)pt*SEG*KNN);
  const int4*   ip = (const int4*)(pi + (size_t)pt*SEG*KNN);
  float bd[KNN]; int bi[KNN];
#pragma unroll
  for(int i=0;i<KNN;i++){ bd[i]=__builtin_inff(); bi[i]=0x7fffffff; }
  for(int v=0; v<SEG*KNN/4; v++){
    float4 dv = dp[v];
    int4   iv = ip[v];
    float dd[4] = {dv.x,dv.y,dv.z,dv.w};
    int   ii[4] = {iv.x,iv.y,iv.z,iv.w};
#pragma unroll
    for(int u=0;u<4;u++){
      float d = dd[u]; int id = ii[u];
      if(d < bd[KNN-1]){
        bd[KNN-1]=d; bi[KNN-1]=id;
#pragma unroll
        for(int i=KNN-2;i>=0;i--){
          if(bd[i+1] < bd[i]){
            float td=bd[i]; bd[i]=bd[i+1]; bd[i+1]=td;
            int ti=bi[i]; bi[i]=bi[i+1]; bi[i+1]=ti;
          }
        }
      }
    }
  }
#pragma unroll
  for(int r=0;r<KNN;r++) idxo[pt*KNN + r] = bi[r];
}

// ---------------- weightnet stage 1 ----------------
__global__ __launch_bounds__(256) void k_wn1(
    const float* __restrict__ xyz, const int* __restrict__ idx,
    const float* __restrict__ W, const float* __restrict__ Bv,
    float* __restrict__ hout, float* __restrict__ partial)
{
  int t = threadIdx.x;
  int e = blockIdx.x*256 + t;
  int pt = e/KNN;
  int b = pt>>13, n = pt & (NPTS-1);
  int m = idx[e];
  const float* xb = xyz + (size_t)b*NPTS*3;
  float gx = xb[3*m]-xb[3*n], gy = xb[3*m+1]-xb[3*n+1], gz = xb[3*m+2]-xb[3*n+2];
  float v[8];
#pragma unroll
  for(int j=0;j<8;j++){
    float d = fmaf(gz, W[3*j+2], fmaf(gy, W[3*j+1], gx*W[3*j]));
    v[j] = d + Bv[j];
    hout[(size_t)e*8 + j] = v[j];
  }
  __shared__ float red[4][2][8];
  int wave = t>>6, lane = t&63;
#pragma unroll
  for(int j=0;j<8;j++){
    float s = wred(v[j]);
    float q = wred(v[j]*v[j]);
    if(lane==0){ red[wave][0][j]=s; red[wave][1][j]=q; }
  }
  __syncthreads();
  if(t < 16){
    int isq = t>>3, c = t&7;
    partial[blockIdx.x*16 + t] =
      red[0][isq][c]+red[1][isq][c]+red[2][isq][c]+red[3][isq][c];
  }
}

// ---------------- weightnet stage 2/3 with fused stats-finalize preamble ----------------
template<int CI, int CO>
__global__ __launch_bounds__(256) void k_wn23(
    const float* __restrict__ hin, const float* __restrict__ partialIn,
    int nb, float cnt,
    const float* __restrict__ W, const float* __restrict__ Bv,
    float* __restrict__ hout, float* __restrict__ partialOut)
{
  __shared__ float sa[256], qa[256];
  __shared__ float stl[2*CI];
  int t = threadIdx.x;
  // finalize stats of previous stage (replicated per block)
  {
    int c = t % CI;
    int r0 = t / CI;
    int stride = 256 / CI;
    float s=0.f, q=0.f;
    for(int r=r0; r<nb; r+=stride){
      s += partialIn[r*2*CI + c];
      q += partialIn[r*2*CI + CI + c];
    }
    sa[t]=s; qa[t]=q;
    __syncthreads();
    if(t < CI){
      for(int g=1; g<stride; g++){ s += sa[t+g*CI]; q += qa[t+g*CI]; }
      float mean = s/cnt;
      float var  = q/cnt - mean*mean;
      stl[t]    = mean;
      stl[CI+t] = 1.0f/sqrtf(var + 1e-5f);
    }
    __syncthreads();
  }
  int e = blockIdx.x*256 + t;
  float x[CI];
#pragma unroll
  for(int i=0;i<CI;i++){
    float v = (hin[(size_t)e*CI + i] - stl[i])*stl[CI+i];
    x[i] = v>0.f? v : 0.f;
  }
  float v[CO];
#pragma unroll
  for(int j=0;j<CO;j++){
    float d = 0.f;
#pragma unroll
    for(int i=0;i<CI;i++) d = fmaf(x[i], W[j*CI+i], d);
    v[j] = d + Bv[j];
    hout[(size_t)e*CO + j] = v[j];
  }
  __shared__ float red[4][2][CO];
  int wave = t>>6, lane = t&63;
#pragma unroll
  for(int j=0;j<CO;j++){
    float s = wred(v[j]);
    float q = wred(v[j]*v[j]);
    if(lane==0){ red[wave][0][j]=s; red[wave][1][j]=q; }
  }
  __syncthreads();
  if(t < 2*CO){
    int isq = t/CO, c = t%CO;
    partialOut[blockIdx.x*2*CO + t] =
      red[0][isq][c]+red[1][isq][c]+red[2][isq][c]+red[3][isq][c];
  }
}

// ---------------- finalize stats ----------------
__global__ __launch_bounds__(256) void k_fin(
    const float* __restrict__ partial, float* __restrict__ st,
    int C, int nb, float cnt)
{
  __shared__ float sa[256], qa[256];
  int t = threadIdx.x;
  int c = t % C;
  int r0 = t / C;
  int stride = 256 / C;
  float s=0.f, q=0.f;
  for(int r=r0; r<nb; r+=stride){
    s += partial[r*2*C + c];
    q += partial[r*2*C + C + c];
  }
  sa[t]=s; qa[t]=q;
  __syncthreads();
  if(t < C){
    for(int g=1; g<stride; g++){ s += sa[t+g*C]; q += qa[t+g*C]; }
    float mean = s/cnt;
    float var  = q/cnt - mean*mean;
    st[t]   = mean;
    st[C+t] = 1.0f/sqrtf(var + 1e-5f);
  }
}

// ---------------- prep W: f32 -> bf16, K-padded, [128][KP] ----------------
__global__ __launch_bounds__(256) void k_prepW(
    const float* __restrict__ linW, u16* __restrict__ Wh, int AW, int KP)
{
  int e = blockIdx.x*256 + threadIdx.x;
  if(e >= 128*KP) return;
  int o = e / KP, k = e - o*KP;
  float w = (k < AW) ? linW[o*AW + k] : 0.f;
  Wh[e] = f2b(w);
}

// ---------------- build A (gather + weightnet einsum) -> bf16 [row][KP] ----------------
template<int CIN, int XSTRIDE, int KP>
__global__ __launch_bounds__(256) void k_buildA(
    const float* __restrict__ xin, const float* __restrict__ xyz,
    const int* __restrict__ idx, const float* __restrict__ wpre,
    const float* __restrict__ st3, u16* __restrict__ Abuf, int c0)
{
  constexpr int P = 16;
  constexpr int CPTS = CIN-3;
  constexpr int CPAD = KP/16;
  __shared__ float wm[P][KNN][16];
  __shared__ float gxs[P][KNN][3];
  __shared__ int   si[P][KNN];
  __shared__ float sm3[16], sr3[16];
  int t = threadIdx.x;
  int pt0 = c0 + blockIdx.x*P;
  int b = pt0 >> 13;
  const float* xb = xyz + (size_t)b*NPTS*3;
  if(t<16){ sm3[t]=st3[t]; sr3[t]=st3[16+t]; }
  for(int e=t; e<P*KNN; e+=256){
    int p = e/KNN, k = e - p*KNN;
    int n = (pt0+p)&(NPTS-1);
    int m = idx[(pt0+p)*KNN+k];
    si[p][k]=m;
    gxs[p][k][0]=xb[3*m]  -xb[3*n];
    gxs[p][k][1]=xb[3*m+1]-xb[3*n+1];
    gxs[p][k][2]=xb[3*m+2]-xb[3*n+2];
  }
  __syncthreads();
  for(int e=t; e<P*KNN*16; e+=256){
    int p = e/(KNN*16); int r = e - p*(KNN*16); int k = r>>4, wn = r&15;
    float v = (wpre[((size_t)(pt0+p)*KNN + k)*16 + wn] - sm3[wn]) * sr3[wn];
    wm[p][k][wn] = v>0.f? v:0.f;
  }
  __syncthreads();
  for(int it=t; it<P*CPAD; it+=256){
    int p = it/CPAD, c = it - p*CPAD;
    u32 u[8];
    if(c < CIN){
      float g[KNN];
      if(c < CPTS){
#pragma unroll
        for(int k=0;k<KNN;k++)
          g[k] = xin[(size_t)((b<<13) + si[p][k])*XSTRIDE + c];
      } else {
        int cc = c - CPTS;
#pragma unroll
        for(int k=0;k<KNN;k++) g[k] = gxs[p][k][cc];
      }
      float a[16];
#pragma unroll
      for(int wn=0; wn<16; wn++){
        float s = 0.f;
#pragma unroll
        for(int k=0;k<KNN;k++) s = fmaf(g[k], wm[p][k][wn], s);
        a[wn] = s;
      }
#pragma unroll
      for(int j=0;j<8;j++)
        u[j] = (u32)f2b(a[2*j]) | ((u32)f2b(a[2*j+1])<<16);
    } else {
#pragma unroll
      for(int j=0;j<8;j++) u[j]=0;
    }
    u32* dst = (u32*)(Abuf + ((size_t)(blockIdx.x*P + p)*KP + c*16));
    uint4 v0 = make_uint4(u[0],u[1],u[2],u[3]);
    uint4 v1 = make_uint4(u[4],u[5],u[6],u[7]);
    *(uint4*)dst = v0;
    *((uint4*)dst + 1) = v1;
  }
}

// ---------------- MFMA GEMM (single-W, 8 waves) + fused bn stats ----------------
__device__ __forceinline__ void gload16(const void* g, void* l){
  __builtin_amdgcn_global_load_lds(
      (const __attribute__((address_space(1))) u32*)g,
      (__attribute__((address_space(3))) u32*)l, 16, 0, 0);
}

template<int KP>
__global__ __launch_bounds__(512) void k_gemm(
    const u16* __restrict__ Wh, const u16* __restrict__ A,
    const float* __restrict__ linb, float* __restrict__ outp,
    float* __restrict__ partial, int ptBase)
{
  // LDS: Wh dbuf 2x16KB @0, A dbuf 2x8KB @32768  (48 KiB)
  __shared__ __attribute__((aligned(16))) u16 lds[24576];
  constexpr int NT = KP/64;
  int t = threadIdx.x, wave = t>>6, lane = t&63;
  int p0 = blockIdx.x*64;
  const u16* Ab = A + (size_t)p0*KP;

  auto stage = [&](const u16* __restrict__ g, int k0, int ldsByteOff, int rows){
    int nr = (rows*128) >> 13;           // 8KB per 512-thread round
    for(int r=0;r<nr;r++){
      int y  = (r*8 + wave) << 10;
      int yl = y + lane*16;
      int row = yl >> 7;
      int s = (yl >> 4) & 7;
      int c = s ^ (row & 7);
      const u16* src = g + (size_t)row*KP + k0 + c*8;
      gload16(src, (char*)lds + ldsByteOff + y);
    }
  };

  stage(Wh, 0, 0,     128);
  stage(Ab, 0, 32768, 64);

  f32x4 acc[4];
#pragma unroll
  for(int j=0;j<4;j++) acc[j]=(f32x4)(0.f);

  for(int kt=0; kt<NT; kt++){
    int cur = kt & 1;
    __syncthreads();
    if(kt+1 < NT){
      int nxt = cur^1;
      stage(Wh, (kt+1)*64, nxt*16384,         128);
      stage(Ab, (kt+1)*64, 32768 + nxt*8192,  64);
    }
    const u16* Lw = lds + cur*8192;
    const u16* La = lds + 16384 + cur*4096;
#pragma unroll
    for(int kf=0; kf<2; kf++){
      int cb = kf*4 + (lane>>4);
      bf16x8 af[4];
#pragma unroll
      for(int nf=0; nf<4; nf++){
        int p = nf*16 + (lane&15);
        af[nf] = *(const bf16x8*)(La + p*64 + ((cb ^ (p&7))<<3));
      }
      int row = wave*16 + (lane&15);
      bf16x8 wh = *(const bf16x8*)(Lw + row*64 + ((cb ^ (row&7))<<3));
#pragma unroll
      for(int nf=0; nf<4; nf++)
        acc[nf] = __builtin_amdgcn_mfma_f32_16x16x32_bf16(wh, af[nf], acc[nf], 0,0,0);
    }
  }

  // epilogue: bias + store + per-block bn partials
  int gb = (ptBase>>6) + blockIdx.x;
  int q = lane>>4, lc = lane&15;
  int obase = wave*16 + q*4;
#pragma unroll
  for(int r=0;r<4;r++){
    int o = obase + r;
    float bo = linb[o];
    float sv = 0.f, qv = 0.f;
#pragma unroll
    for(int nf=0; nf<4; nf++){
      float x = acc[nf][r] + bo;
      outp[(size_t)(ptBase + p0 + nf*16 + lc)*128 + o] = x;
      sv += x; qv = fmaf(x,x,qv);
    }
#pragma unroll
    for(int off=8; off>0; off>>=1){
      sv += __shfl_down(sv,off);
      qv += __shfl_down(qv,off);
    }
    if(lc==0){
      partial[gb*256 + o]       = sv;
      partial[gb*256 + 128 + o] = qv;
    }
  }
}

__global__ __launch_bounds__(256) void k_pfin(
    const float* __restrict__ outp, const float* __restrict__ st,
    float* __restrict__ xout)
{
  int e = blockIdx.x*256 + threadIdx.x;
  int c = e & 127;
  float v = (outp[e]-st[c])*st[128+c];
  xout[e] = v>=0.f? v : 0.1f*v;
}

// ---------------- fused mlp0 + mlp1 + fc (8 waves) ----------------
__global__ __launch_bounds__(512) void k_mlp(
    const float* __restrict__ x2,
    const float* __restrict__ W0, const float* __restrict__ B0,
    const float* __restrict__ W1, const float* __restrict__ B1,
    const float* __restrict__ Wf, const float* __restrict__ Bf,
    float* __restrict__ dout)
{
  __shared__ float w0l[128*129];
  __shared__ float w1l[128*65];
  __shared__ float xt [128*65];
  __shared__ float m1l[64*65];
  int t = threadIdx.x;
  int pt0 = blockIdx.x*64;
  int b = pt0 >> 13, n0 = pt0 & (NPTS-1);
  for(int e=t; e<128*128; e+=512){ int o=e>>7, j=e&127; w0l[j*129+o] = W0[e]; }
  for(int e=t; e<64*128;  e+=512){ int o=e>>7, j=e&127; w1l[j*65+o]  = W1[e]; }
  for(int e=t; e<64*128;  e+=512){ int p=e>>7, j=e&127; xt[j*65+p]   = x2[(size_t)(pt0+p)*128 + j]; }
  __syncthreads();
  int p = t&63, wv = t>>6;   // wv in 0..7
  float acc[16];
#pragma unroll
  for(int i=0;i<16;i++) acc[i]=0.f;
  for(int j=0;j<128;j++){
    float xv = xt[j*65+p];
#pragma unroll
    for(int i=0;i<16;i++)
      acc[i] = fmaf(w0l[j*129 + wv*16 + i], xv, acc[i]);
  }
  __syncthreads();
#pragma unroll
  for(int i=0;i<16;i++){
    int o = wv*16+i;
    float v = acc[i] + B0[o];
    v = v>=0.f? v : 0.1f*v;
    xt[o*65 + p] = v;
  }
  __syncthreads();
  float a2[8];
#pragma unroll
  for(int i=0;i<8;i++) a2[i]=0.f;
  for(int j=0;j<128;j++){
    float xv = xt[j*65+p];
#pragma unroll
    for(int i=0;i<8;i++)
      a2[i] = fmaf(w1l[j*65 + wv*8 + i], xv, a2[i]);
  }
#pragma unroll
  for(int i=0;i<8;i++){
    int o = wv*8+i;
    float v = a2[i] + B1[o];
    v = v>=0.f? v : 0.1f*v;
    dout[(size_t)(b*64+o)*NPTS + n0 + p] = v;
    m1l[o*65+p] = v;
  }
  __syncthreads();
  if(t < 192){
    int o = t/64, pp = t%64;
    float a = Bf[o];
    for(int j=0;j<64;j++) a = fmaf(Wf[o*64+j], m1l[j*65+pp], a);
    a = fminf(fmaxf(a, -200.f), 200.f);
    dout[(size_t)NBATCH*64*NPTS + (size_t)(b*3+o)*NPTS + n0 + pp] = a;
  }
}

extern "C" void kernel_launch(void* const* d_in, const int* in_sizes, int n_in,
                              void* d_out, int out_size, void* d_ws, size_t ws_size,
                              hipStream_t stream)
{
  (void)in_sizes; (void)n_in; (void)out_size;
  const float* xyz   = (const float*)d_in[0];
  const float* feats = (const float*)d_in[1];
  const float* cost  = (const float*)d_in[2];
  const float* flow  = (const float*)d_in[3];
  const float* pw1[2]  = {(const float*)d_in[4],  (const float*)d_in[12]};
  const float* pb1[2]  = {(const float*)d_in[5],  (const float*)d_in[13]};
  const float* pw2[2]  = {(const float*)d_in[6],  (const float*)d_in[14]};
  const float* pb2[2]  = {(const float*)d_in[7],  (const float*)d_in[15]};
  const float* pw3[2]  = {(const float*)d_in[8],  (const float*)d_in[16]};
  const float* pb3[2]  = {(const float*)d_in[9],  (const float*)d_in[17]};
  const float* plW[2]  = {(const float*)d_in[10], (const float*)d_in[18]};
  const float* plb[2]  = {(const float*)d_in[11], (const float*)d_in[19]};
  const float* m0W = (const float*)d_in[20];
  const float* m0b = (const float*)d_in[21];
  const float* m1W = (const float*)d_in[22];
  const float* m1b = (const float*)d_in[23];
  const float* fcW = (const float*)d_in[24];
  const float* fcb = (const float*)d_in[25];
  float* out = (float*)d_out;

  const int KP0 = 3200, AW0 = 3168;
  const int KP1 = 2112, AW1 = 2096;

  float* ws = (float*)d_ws;
  size_t o = 0;
  float* xin0 = ws + o; o += (size_t)NPT*196;
  int*   idx  = (int*)(ws + o); o += (size_t)NPT*KNN + 3;
  o &= ~(size_t)3;
  float* thr  = ws + o; o += (size_t)NPT;
  float* pd   = ws + o; o += (size_t)NPT*SEG*KNN;
  int*   pi   = (int*)(ws + o); o += (size_t)NPT*SEG*KNN;
  float* h1   = ws + o; o += (size_t)NPT*KNN*8;
  float* h2   = ws + o; o += (size_t)NPT*KNN*8;
  float* wpre = ws + o; o += (size_t)NPT*KNN*16;
  float* part1 = ws + o; o += 576*16;
  float* part2 = ws + o; o += 576*16;
  float* part3 = ws + o; o += 576*32;
  float* parto = ws + o; o += 65536;
  float* st3  = ws + o; o += 32;
  float* sto  = ws + o; o += 256;
  float* outp = ws + o; o += (size_t)NPT*128;
  float* x1   = ws + o; o += (size_t)NPT*128;
  float* x2   = ws + o; o += (size_t)NPT*128;
  u16* Wh0 = (u16*)(ws + o); o += (size_t)128*KP0/2;
  u16* Wh1 = (u16*)(ws + o); o += (size_t)128*KP1/2;
  u16* Abuf = (u16*)(ws + o);
  size_t used_bytes = o*4;
  size_t avail = ws_size > used_bytes ? ws_size - used_bytes : 0;
  int npc = NPT;
  while(npc > 1024 && (size_t)npc*KP0*2 > avail) npc >>= 1;

  k_build_xin<<<NPT/64, 256, 0, stream>>>(feats, cost, flow, xin0);
  k_thr<<<256, 256, 0, stream>>>(xyz, thr);
  k_knn_part<<<64*SEG, 256, 0, stream>>>(xyz, thr, pd, pi);
  k_knn_merge<<<NPT/256, 256, 0, stream>>>(pd, pi, idx);

  k_prepW<<<(128*KP0+255)/256, 256, 0, stream>>>(plW[0], Wh0, AW0, KP0);
  k_prepW<<<(128*KP1+255)/256, 256, 0, stream>>>(plW[1], Wh1, AW1, KP1);

  const float cnt1 = (float)(NPT*KNN);
  const float cnto = (float)NPT;

  for(int L=0; L<2; ++L){
    k_wn1<<<576,256,0,stream>>>(xyz, idx, pw1[L], pb1[L], h1, part1);
    k_wn23<8,8><<<576,256,0,stream>>>(h1, part1, 576, cnt1, pw2[L], pb2[L], h2, part2);
    k_wn23<8,16><<<576,256,0,stream>>>(h2, part2, 576, cnt1, pw3[L], pb3[L], wpre, part3);
    k_fin<<<1,256,0,stream>>>(part3, st3, 16, 576, cnt1);
    for(int c0 = 0; c0 < NPT; c0 += npc){
      if(L==0){
        k_buildA<198,196,KP0><<<npc/16,256,0,stream>>>(xin0, xyz, idx, wpre, st3, Abuf, c0);
        k_gemm<KP0><<<npc/64,512,0,stream>>>(Wh0, Abuf, plb[0], outp, parto, c0);
      } else {
        k_buildA<131,128,KP1><<<npc/16,256,0,stream>>>(x1, xyz, idx, wpre, st3, Abuf, c0);
        k_gemm<KP1><<<npc/64,512,0,stream>>>(Wh1, Abuf, plb[1], outp, parto, c0);
      }
    }
    k_fin<<<1,256,0,stream>>>(parto, sto, 128, NPT/64, cnto);
    k_pfin<<<NPT*128/256,256,0,stream>>>(outp, sto, (L==0)? x1 : x2);
  }

  k_mlp<<<NPT/64,512,0,stream>>>(x2, m0W,m0b, m1W,m1b, fcW,fcb, out);
}